// Round 1
// baseline (620.616 us; speedup 1.0000x reference)
//
#include <hip/hip_runtime.h>

// SAN Subtraction: out[n,c,kh*7+kw, h*112+w] = x[n,c,h,w] - x[n,c,refl(h+kh-3),refl(w+kw-3)]
// x (4,64,112,112) fp32, reflect padding (jnp 'reflect': t<0 -> -t ; t>D-1 -> 2(D-1)-t).
//
// Restructure vs previous version: one block per (nc, kh). The x-plane (50 KB)
// is staged once into LDS; the kw loop is OUTER so each block emits ONE
// contiguous nontemporal store stream per output plane (fill-like HBM write
// locality) instead of 49 interleaved 1-KiB-granularity streams per wave.

#define NC_   256      // N*C
#define H_    112
#define W_    112
#define K_    7
#define PADV  3
#define HW    12544    // H*W
#define K2_   49

typedef float vf4 __attribute__((ext_vector_type(4)));

__global__ __launch_bounds__(448) void san_sub_kernel(const float* __restrict__ x,
                                                      float* __restrict__ out) {
    __shared__ float sx[HW];            // 50176 B: one full (n,c) plane

    const int bid = blockIdx.x;
    const int nc  = bid / K_;           // 0..255  (consecutive blocks share nc -> L2/L3 reuse)
    const int kh  = bid % K_;           // 0..6
    const int tid = threadIdx.x;        // 0..447  (7 waves)

    const float* __restrict__ xc = x + (size_t)nc * HW;

    // ---- stage full plane into LDS: 3136 vf4 by 448 threads, 7 each ----
    #pragma unroll
    for (int s = 0; s < 7; ++s) {
        int idx = s * 448 + tid;                       // vf4 index, lane-contiguous
        vf4 v = *reinterpret_cast<const vf4*>(xc + idx * 4);
        *reinterpret_cast<vf4*>(&sx[idx * 4]) = v;
    }
    __syncthreads();

    const int trow = tid / 28;          // 0..15
    const int w4   = tid % 28;
    const int w    = w4 * 4;

    // kw OUTER: one output plane at a time -> single linear store stream/block
    for (int kw = 0; kw < K_; ++kw) {
        // reflected column indices — fixed per thread for this kw, hoisted
        int c0, c1, c2, c3;
        {
            int base = w + kw - PADV;
            int cc;
            cc = base + 0; cc = (cc < 0) ? -cc : cc; cc = (cc > W_-1) ? (2*(W_-1) - cc) : cc; c0 = cc;
            cc = base + 1; cc = (cc < 0) ? -cc : cc; cc = (cc > W_-1) ? (2*(W_-1) - cc) : cc; c1 = cc;
            cc = base + 2; cc = (cc < 0) ? -cc : cc; cc = (cc > W_-1) ? (2*(W_-1) - cc) : cc; c2 = cc;
            cc = base + 3; cc = (cc < 0) ? -cc : cc; cc = (cc > W_-1) ? (2*(W_-1) - cc) : cc; c3 = cc;
        }
        float* __restrict__ po = out + ((size_t)nc * K2_ + (size_t)(kh * K_ + kw)) * HW;

        #pragma unroll
        for (int i = 0; i < 7; ++i) {
            int h = i * 16 + trow;                     // covers 0..111 exactly once
            int r = h + kh - PADV;                     // reflected source row
            r = (r < 0) ? -r : r;
            r = (r > H_-1) ? (2*(H_-1) - r) : r;
            const float* srow = &sx[r * W_];
            vf4 center = *reinterpret_cast<const vf4*>(&sx[h * W_ + w]);
            vf4 o;
            o.x = center.x - srow[c0];
            o.y = center.y - srow[c1];
            o.z = center.z - srow[c2];
            o.w = center.w - srow[c3];
            // lanes of a wave -> perfectly linear 1 KiB; block -> 7 KB chunks/plane
            __builtin_nontemporal_store(o, reinterpret_cast<vf4*>(po + h * W_ + w));
        }
    }
}

extern "C" void kernel_launch(void* const* d_in, const int* in_sizes, int n_in,
                              void* d_out, int out_size, void* d_ws, size_t ws_size,
                              hipStream_t stream) {
    const float* x = (const float*)d_in[0];
    float* out = (float*)d_out;
    dim3 grid(NC_ * K_);   // 1792 blocks: (nc, kh); 7 per CU, 3 resident (LDS-bound)
    dim3 block(448);       // 7 waves
    san_sub_kernel<<<grid, block, 0, stream>>>(x, out);
}

// Round 2
// 614.296 us; speedup vs baseline: 1.0103x; 1.0103x over previous
//
#include <hip/hip_runtime.h>

// SAN Subtraction: out[n,c,kh*7+kw, h*112+w] = x[n,c,h,w] - x[n,c,refl(h+kh-3),refl(w+kw-3)]
// x (4,64,112,112) fp32, reflect padding (jnp 'reflect': t<0 -> -t ; t>D-1 -> 2(D-1)-t).
//
// Round 2: identical to round 1 EXCEPT plain stores instead of
// __builtin_nontemporal_store. Theory: nt stores bypass L2 write-combining and
// cap the store path at ~3 TB/s (both prior kernels: 214 µs kernel time despite
// totally different read paths / store orderings), while the harness's plain-store
// fill kernel hits 6.2 TB/s on the same buffer.

#define NC_   256      // N*C
#define H_    112
#define W_    112
#define K_    7
#define PADV  3
#define HW    12544    // H*W
#define K2_   49

typedef float vf4 __attribute__((ext_vector_type(4)));

__global__ __launch_bounds__(448) void san_sub_kernel(const float* __restrict__ x,
                                                      float* __restrict__ out) {
    __shared__ float sx[HW];            // 50176 B: one full (n,c) plane

    const int bid = blockIdx.x;
    const int nc  = bid / K_;           // 0..255  (consecutive blocks share nc -> L2/L3 reuse)
    const int kh  = bid % K_;           // 0..6
    const int tid = threadIdx.x;        // 0..447  (7 waves)

    const float* __restrict__ xc = x + (size_t)nc * HW;

    // ---- stage full plane into LDS: 3136 vf4 by 448 threads, 7 each ----
    #pragma unroll
    for (int s = 0; s < 7; ++s) {
        int idx = s * 448 + tid;                       // vf4 index, lane-contiguous
        vf4 v = *reinterpret_cast<const vf4*>(xc + idx * 4);
        *reinterpret_cast<vf4*>(&sx[idx * 4]) = v;
    }
    __syncthreads();

    const int trow = tid / 28;          // 0..15
    const int w4   = tid % 28;
    const int w    = w4 * 4;

    // kw OUTER: one output plane at a time -> single linear store stream/block
    for (int kw = 0; kw < K_; ++kw) {
        // reflected column indices — fixed per thread for this kw, hoisted
        int c0, c1, c2, c3;
        {
            int base = w + kw - PADV;
            int cc;
            cc = base + 0; cc = (cc < 0) ? -cc : cc; cc = (cc > W_-1) ? (2*(W_-1) - cc) : cc; c0 = cc;
            cc = base + 1; cc = (cc < 0) ? -cc : cc; cc = (cc > W_-1) ? (2*(W_-1) - cc) : cc; c1 = cc;
            cc = base + 2; cc = (cc < 0) ? -cc : cc; cc = (cc > W_-1) ? (2*(W_-1) - cc) : cc; c2 = cc;
            cc = base + 3; cc = (cc < 0) ? -cc : cc; cc = (cc > W_-1) ? (2*(W_-1) - cc) : cc; c3 = cc;
        }
        float* __restrict__ po = out + ((size_t)nc * K2_ + (size_t)(kh * K_ + kw)) * HW;

        #pragma unroll
        for (int i = 0; i < 7; ++i) {
            int h = i * 16 + trow;                     // covers 0..111 exactly once
            int r = h + kh - PADV;                     // reflected source row
            r = (r < 0) ? -r : r;
            r = (r > H_-1) ? (2*(H_-1) - r) : r;
            const float* srow = &sx[r * W_];
            vf4 center = *reinterpret_cast<const vf4*>(&sx[h * W_ + w]);
            vf4 o;
            o.x = center.x - srow[c0];
            o.y = center.y - srow[c1];
            o.z = center.z - srow[c2];
            o.w = center.w - srow[c3];
            // PLAIN store: let L2 write-combine and stream to HBM (fill-proven 6.2 TB/s path)
            *reinterpret_cast<vf4*>(po + h * W_ + w) = o;
        }
    }
}

extern "C" void kernel_launch(void* const* d_in, const int* in_sizes, int n_in,
                              void* d_out, int out_size, void* d_ws, size_t ws_size,
                              hipStream_t stream) {
    const float* x = (const float*)d_in[0];
    float* out = (float*)d_out;
    dim3 grid(NC_ * K_);   // 1792 blocks: (nc, kh); 7 per CU, 3 resident (LDS-bound)
    dim3 block(448);       // 7 waves
    san_sub_kernel<<<grid, block, 0, stream>>>(x, out);
}